// Round 1
// baseline (3457.690 us; speedup 1.0000x reference)
//
#include <hip/hip_runtime.h>
#include <hip/hip_bf16.h>
#include <math.h>

#define B_  8
#define C_  128
#define CH_ 64
#define LX_ 128
#define LY_ 1024

// ---------------- K0: transpose W_down [128][64] -> wdT [64][128] ----------------
__global__ __launch_bounds__(256) void k0_transpose(const float* __restrict__ wd,
                                                    float* __restrict__ wdT) {
    int t = blockIdx.x * 256 + threadIdx.x;
    if (t < CH_ * C_) {
        int k = t >> 7, c = t & 127;
        wdT[t] = wd[c * CH_ + k];   // wdT[k][c] = W_down[c][k]
    }
}

// ---------------- K1: att = x^T @ W + b  for drug and prot ----------------
// att[b,l,d] = sum_c in[b,c,l] * W[c,d] + bias[d]
// grid: 256 drug-blocks (4 rows each) + 2048 prot-blocks (4 rows each); block = 128 thr
__global__ __launch_bounds__(128) void k1_att(
    const float* __restrict__ x, const float* __restrict__ y,
    const float* __restrict__ Wd, const float* __restrict__ bd,
    const float* __restrict__ Wp, const float* __restrict__ bp,
    float* __restrict__ datt, float* __restrict__ patt)
{
    const int blk = blockIdx.x;
    const float* src; const float* W; const float* bias; float* dst; int L;
    int b, l0;
    if (blk < 256) {                       // drug rows: b*LX + l
        int row0 = blk * 4; b = row0 >> 7; l0 = row0 & 127;
        src = x; W = Wd; bias = bd; dst = datt; L = LX_;
    } else {
        int row0 = (blk - 256) * 4; b = row0 >> 10; l0 = row0 & 1023;
        src = y; W = Wp; bias = bp; dst = patt; L = LY_;
    }
    __shared__ float col[4][128];
    const int t = threadIdx.x;             // 128 threads = d / c index
    {
        const float* sp = src + ((long)b * C_ + t) * L + l0;
        float4 v = *(const float4*)sp;     // 4 consecutive l, 16B aligned
        col[0][t] = v.x; col[1][t] = v.y; col[2][t] = v.z; col[3][t] = v.w;
    }
    __syncthreads();
    float acc0 = bias[t], acc1 = acc0, acc2 = acc0, acc3 = acc0;
    #pragma unroll 8
    for (int c = 0; c < 128; ++c) {
        float w = W[c * 128 + t];          // coalesced, L1/L2-resident
        float s0 = col[0][c], s1 = col[1][c], s2 = col[2][c], s3 = col[3][c];
        acc0 = fmaf(s0, w, acc0); acc1 = fmaf(s1, w, acc1);
        acc2 = fmaf(s2, w, acc2); acc3 = fmaf(s3, w, acc3);
    }
    float* dp = dst + ((long)b * L + l0) * C_ + t;
    dp[0] = acc0; dp[C_] = acc1; dp[2 * C_] = acc2; dp[3 * C_] = acc3;
}

// ---------------- K2: fused pair-MLP + local axis reductions ----------------
// block = (b, lx-tile of 32, ly-tile of 32); 256 threads, lane-per-pair (4 pairs/thread)
// Diagonal mapping: lx = t&31, ly = (g + 8j + lx)&31  -> LDS accum writes are
// bank-spread for BOTH comp (row=lx) and prot (row=ly) without runtime reg indexing.
__global__ __launch_bounds__(256) void k2_main(
    const float* __restrict__ datt, const float* __restrict__ patt,
    const float* __restrict__ wdT,  const float* __restrict__ bdown,
    const float* __restrict__ wup,  const float* __restrict__ bup,
    float* __restrict__ comp_part,  float* __restrict__ prot_part)
{
    const int lyblk = blockIdx.x;   // 0..31
    const int lxblk = blockIdx.y;   // 0..3
    const int b     = blockIdx.z;   // 0..7
    const int t     = threadIdx.x;

    __shared__ float dT[32][132];    // pad to 132 (16B-aligned rows, bank-spread)
    __shared__ float pT[32][132];
    __shared__ float compA[32][129]; // pad 129: row-spread banks for b32 atomics
    __shared__ float protA[32][129];

    {
        const float* dsrc = datt + ((long)b * LX_ + lxblk * 32) * C_;
        const float* psrc = patt + ((long)b * LY_ + lyblk * 32) * C_;
        for (int u = t * 4; u < 32 * C_; u += 256 * 4) {
            int r = u >> 7, c = u & 127;
            *(float4*)&dT[r][c] = *(const float4*)(dsrc + u);
            *(float4*)&pT[r][c] = *(const float4*)(psrc + u);
        }
        for (int u = t; u < 32 * 129; u += 256) {
            (&compA[0][0])[u] = 0.f;
            (&protA[0][0])[u] = 0.f;
        }
    }
    __syncthreads();

    const int lx = t & 31;
    const int g  = t >> 5;          // 0..7

    #pragma unroll 1
    for (int j = 0; j < 4; ++j) {
        const int ly = (g + 8 * j + lx) & 31;    // diagonal coverage, all pairs once
        #pragma unroll 1
        for (int kc = 0; kc < 2; ++kc) {         // h in 2 chunks of 32
            float hh[32];
            #pragma unroll
            for (int kk = 0; kk < 32; ++kk) hh[kk] = bdown[kc * 32 + kk];

            #pragma unroll 1
            for (int cc = 0; cc < 4; ++cc) {     // c in 4 chunks of 32
                float s[32];
                #pragma unroll
                for (int i4 = 0; i4 < 8; ++i4) {
                    float4 dv = *(const float4*)&dT[lx][cc * 32 + i4 * 4];
                    float4 pv = *(const float4*)&pT[ly][cc * 32 + i4 * 4];
                    s[i4 * 4 + 0] = fmaxf(dv.x + pv.x, 0.f);
                    s[i4 * 4 + 1] = fmaxf(dv.y + pv.y, 0.f);
                    s[i4 * 4 + 2] = fmaxf(dv.z + pv.z, 0.f);
                    s[i4 * 4 + 3] = fmaxf(dv.w + pv.w, 0.f);
                }
                const float* wrow = wdT + (kc * 32) * C_ + cc * 32;
                #pragma unroll
                for (int kk = 0; kk < 32; ++kk) {
                    const float* w = wrow + kk * C_;   // wave-uniform -> s_load
                    #pragma unroll
                    for (int i = 0; i < 32; ++i)
                        hh[kk] = fmaf(s[i], w[i], hh[kk]);
                }
            }
            #pragma unroll
            for (int kk = 0; kk < 32; ++kk) hh[kk] = fmaxf(hh[kk], 0.f);

            // phase 2: a_chunk = hh @ W_up[kc-chunk], accumulate into LDS
            #pragma unroll 1
            for (int cc = 0; cc < 4; ++cc) {
                float a[32];
                if (kc == 0) {
                    #pragma unroll
                    for (int i = 0; i < 32; ++i) a[i] = bup[cc * 32 + i];
                } else {
                    #pragma unroll
                    for (int i = 0; i < 32; ++i) a[i] = 0.f;
                }
                const float* wrow = wup + (kc * 32) * C_ + cc * 32;
                #pragma unroll
                for (int kk = 0; kk < 32; ++kk) {
                    const float* w = wrow + kk * C_;   // wave-uniform -> s_load
                    #pragma unroll
                    for (int i = 0; i < 32; ++i)
                        a[i] = fmaf(hh[kk], w[i], a[i]);
                }
                #pragma unroll
                for (int i = 0; i < 32; ++i)
                    atomicAdd(&compA[lx][cc * 32 + i], a[i]);
                #pragma unroll
                for (int i = 0; i < 32; ++i)
                    atomicAdd(&protA[ly][cc * 32 + i], a[i]);
            }
        }
    }
    __syncthreads();
    {
        float* cp = comp_part + ((long)lyblk * B_ * LX_ + (long)b * LX_ + lxblk * 32) * C_;
        float* pp = prot_part + ((long)lxblk * B_ * LY_ + (long)b * LY_ + lyblk * 32) * C_;
        for (int u = t; u < 32 * C_; u += 256) {
            int r = u >> 7, c = u & 127;
            cp[u] = compA[r][c];
            pp[u] = protA[r][c];
        }
    }
}

// ---------------- K3: reduce partials -> gate -> transpose -> out ----------------
// block handles (b, 32 l-rows, all 128 c). out[b][c][l] = x[b][c][l]*(0.5 + gate)
__global__ __launch_bounds__(256) void k3_gate(
    const float* __restrict__ part, long pstride, int nparts, float invN,
    const float* __restrict__ xin, float* __restrict__ outp, int L)
{
    const int b = blockIdx.y, l0 = blockIdx.x * 32;
    __shared__ float gg[32][129];
    const float* p0 = part + ((long)b * L + l0) * C_;
    for (int u = threadIdx.x; u < 32 * C_; u += 256) {
        float acc = 0.f;
        for (int q = 0; q < nparts; ++q) acc += p0[(long)q * pstride + u];
        acc *= invN;
        float sg = 1.f / (1.f + expf(-acc));
        gg[u >> 7][u & 127] = sg * tanhf(acc);
    }
    __syncthreads();
    for (int u = threadIdx.x; u < 32 * C_; u += 256) {
        int c = u >> 5, l = u & 31;
        long idx = ((long)b * C_ + c) * L + l0 + l;
        outp[idx] = xin[idx] * (0.5f + gg[l][c]);
    }
}

extern "C" void kernel_launch(void* const* d_in, const int* in_sizes, int n_in,
                              void* d_out, int out_size, void* d_ws, size_t ws_size,
                              hipStream_t stream) {
    const float* x     = (const float*)d_in[0];
    const float* y     = (const float*)d_in[1];
    const float* Wdrug = (const float*)d_in[2];
    const float* bdrug = (const float*)d_in[3];
    const float* Wprot = (const float*)d_in[4];
    const float* bprot = (const float*)d_in[5];
    const float* Wdown = (const float*)d_in[6];
    const float* bdown = (const float*)d_in[7];
    const float* Wup   = (const float*)d_in[8];
    const float* bup   = (const float*)d_in[9];
    float* out = (float*)d_out;
    float* ws  = (float*)d_ws;

    float* datt      = ws;                 // B*LX*C           = 131072
    float* patt      = ws + 131072;        // B*LY*C           = 1048576
    float* wdT       = ws + 1179648;       // CH*C             = 8192
    float* comp_part = ws + 1187840;       // 32 * B*LX*C      = 4194304
    float* prot_part = ws + 5382144;       // 4  * B*LY*C      = 4194304
    // total = 9,576,448 floats = 38.3 MB

    hipLaunchKernelGGL(k0_transpose, dim3(32), dim3(256), 0, stream, Wdown, wdT);
    hipLaunchKernelGGL(k1_att, dim3(2304), dim3(128), 0, stream,
                       x, y, Wdrug, bdrug, Wprot, bprot, datt, patt);
    hipLaunchKernelGGL(k2_main, dim3(32, 4, 8), dim3(256), 0, stream,
                       datt, patt, wdT, bdown, Wup, bup, comp_part, prot_part);
    hipLaunchKernelGGL(k3_gate, dim3(4, 8), dim3(256), 0, stream,
                       comp_part, (long)(B_ * LX_ * C_), 32, 1.f / 1024.f,
                       x, out, LX_);
    hipLaunchKernelGGL(k3_gate, dim3(32, 8), dim3(256), 0, stream,
                       prot_part, (long)(B_ * LY_ * C_), 4, 1.f / 128.f,
                       y, out + B_ * C_ * LX_, LY_);
}

// Round 2
// 136.392 us; speedup vs baseline: 25.3512x; 25.3512x over previous
//
#include <hip/hip_runtime.h>
#include <hip/hip_bf16.h>
#include <math.h>

#define B_  8
#define C_  128
#define CH_ 64
#define LX_ 128
#define LY_ 1024

typedef __attribute__((ext_vector_type(8))) short short8;
typedef __attribute__((ext_vector_type(4))) float f32x4;

static __device__ __forceinline__ short f2bf(float f) {
    return __builtin_bit_cast(short, __float2bfloat16(f));
}

// ---------------- zero: 576 blocks x 256 thr x float4 = 589824 floats ----------------
__global__ __launch_bounds__(256) void k_zero(float4* __restrict__ p) {
    p[blockIdx.x * 256 + threadIdx.x] = (float4){0.f, 0.f, 0.f, 0.f};
}

// ---------------- K1: att = x^T @ W + b  (unchanged from R0, proven correct) ----------
__global__ __launch_bounds__(128) void k1_att(
    const float* __restrict__ x, const float* __restrict__ y,
    const float* __restrict__ Wd, const float* __restrict__ bd,
    const float* __restrict__ Wp, const float* __restrict__ bp,
    float* __restrict__ datt, float* __restrict__ patt)
{
    const int blk = blockIdx.x;
    const float* src; const float* W; const float* bias; float* dst; int L;
    int b, l0;
    if (blk < 256) {
        int row0 = blk * 4; b = row0 >> 7; l0 = row0 & 127;
        src = x; W = Wd; bias = bd; dst = datt; L = LX_;
    } else {
        int row0 = (blk - 256) * 4; b = row0 >> 10; l0 = row0 & 1023;
        src = y; W = Wp; bias = bp; dst = patt; L = LY_;
    }
    __shared__ float col[4][128];
    const int t = threadIdx.x;
    {
        const float* sp = src + ((long)b * C_ + t) * L + l0;
        float4 v = *(const float4*)sp;
        col[0][t] = v.x; col[1][t] = v.y; col[2][t] = v.z; col[3][t] = v.w;
    }
    __syncthreads();
    float acc0 = bias[t], acc1 = acc0, acc2 = acc0, acc3 = acc0;
    #pragma unroll 8
    for (int c = 0; c < 128; ++c) {
        float w = W[c * 128 + t];
        float s0 = col[0][c], s1 = col[1][c], s2 = col[2][c], s3 = col[3][c];
        acc0 = fmaf(s0, w, acc0); acc1 = fmaf(s1, w, acc1);
        acc2 = fmaf(s2, w, acc2); acc3 = fmaf(s3, w, acc3);
    }
    float* dp = dst + ((long)b * L + l0) * C_ + t;
    dp[0] = acc0; dp[C_] = acc1; dp[2 * C_] = acc2; dp[3 * C_] = acc3;
}

// ---------------- K2: MFMA pair-GEMM + fused axis reductions of relu(h) --------------
// block = (b, 32 lx, 64 ly), 256 thr (4 waves). Wave w owns lxi in [8w, 8w+8).
// GEMM1: s[m,c] @ Wdown[c,kh], m = (lxi,lyi), via mfma 16x16x32 bf16.
// Hy accumulates in regs across the lx inner loop; Hx via shfl-reduce + ds_add.
__global__ __launch_bounds__(256, 2) void k2_main(
    const float* __restrict__ datt, const float* __restrict__ patt,
    const float* __restrict__ wdown, const float* __restrict__ bdown,
    float* __restrict__ Hx, float* __restrict__ Hy)
{
    const int lyblk = blockIdx.x;   // 0..15
    const int lxblk = blockIdx.y;   // 0..3
    const int b     = blockIdx.z;   // 0..7
    const int t     = threadIdx.x;
    const int l     = t & 63;
    const int w     = t >> 6;
    const int g     = l >> 4;       // 0..3
    const int q     = l & 15;       // 0..15

    __shared__ float dT[32][132];   // pad 132: b128 reads hit optimal 8-slot pattern
    __shared__ float pT[64][132];
    __shared__ union {
        ushort wd[128][64];                                 // staged bf16 W_down
        struct { float compH[32][68]; float protH[64][68]; } r;  // later: block partials
    } un;

    // ---- stage datt/patt tiles (f32) and W_down (bf16) ----
    {
        const float* dsrc = datt + ((long)b * LX_ + lxblk * 32) * C_;
        #pragma unroll
        for (int i = 0; i < 4; ++i) {
            int u4 = t + i * 256;
            int r = u4 >> 5, c = (u4 & 31) * 4;
            *(float4*)&dT[r][c] = *(const float4*)(dsrc + u4 * 4);
        }
        const float* psrc = patt + ((long)b * LY_ + lyblk * 64) * C_;
        #pragma unroll
        for (int i = 0; i < 8; ++i) {
            int u4 = t + i * 256;
            int r = u4 >> 5, c = (u4 & 31) * 4;
            *(float4*)&pT[r][c] = *(const float4*)(psrc + u4 * 4);
        }
        #pragma unroll
        for (int i = 0; i < 8; ++i) {
            int u4 = t + i * 256;
            float4 v = *(const float4*)(wdown + u4 * 4);
            ushort* dstp = &((ushort*)un.wd)[u4 * 4];
            dstp[0] = (ushort)f2bf(v.x); dstp[1] = (ushort)f2bf(v.y);
            dstp[2] = (ushort)f2bf(v.z); dstp[3] = (ushort)f2bf(v.w);
        }
    }
    __syncthreads();

    // ---- B-fragments: lane holds B[k = kt*32+g*8+j][n = nt*16+q] ----
    short8 bf[4][4];
    #pragma unroll
    for (int kt = 0; kt < 4; ++kt)
        #pragma unroll
        for (int nt = 0; nt < 4; ++nt)
            #pragma unroll
            for (int j = 0; j < 8; ++j)
                bf[kt][nt][j] = (short)un.wd[kt * 32 + g * 8 + j][nt * 16 + q];
    float bdr[4];
    #pragma unroll
    for (int nt = 0; nt < 4; ++nt) bdr[nt] = bdown[nt * 16 + q];
    __syncthreads();

    // ---- zero the block-partial accumulators (aliases wd) ----
    for (int u2 = t; u2 < 6528; u2 += 256) ((float*)&un.r)[u2] = 0.f;
    __syncthreads();

    #pragma unroll 1
    for (int lyg = 0; lyg < 4; ++lyg) {
        // hoist p-fragments: fixed for the whole lx inner loop
        const float* prow = &pT[lyg * 16 + q][0];
        float pv[4][8];
        #pragma unroll
        for (int kt = 0; kt < 4; ++kt) {
            const float* pp = prow + kt * 32 + g * 8;
            float4 a0 = *(const float4*)pp;
            float4 a1 = *(const float4*)(pp + 4);
            pv[kt][0] = a0.x; pv[kt][1] = a0.y; pv[kt][2] = a0.z; pv[kt][3] = a0.w;
            pv[kt][4] = a1.x; pv[kt][5] = a1.y; pv[kt][6] = a1.z; pv[kt][7] = a1.w;
        }
        float hy[4][4];
        #pragma unroll
        for (int nt = 0; nt < 4; ++nt)
            #pragma unroll
            for (int r = 0; r < 4; ++r) hy[nt][r] = 0.f;

        #pragma unroll 1
        for (int lxr = 0; lxr < 8; ++lxr) {
            const int lxi = w * 8 + lxr;
            const float* drow = &dT[lxi][0];
            // A-fragments: s = relu(d + p) -> bf16. row=q (lyi), k=c=kt*32+g*8+j
            short8 af[4];
            #pragma unroll
            for (int kt = 0; kt < 4; ++kt) {
                const float* dp = drow + kt * 32 + g * 8;
                float4 d0 = *(const float4*)dp;
                float4 d1 = *(const float4*)(dp + 4);
                af[kt][0] = f2bf(fmaxf(d0.x + pv[kt][0], 0.f));
                af[kt][1] = f2bf(fmaxf(d0.y + pv[kt][1], 0.f));
                af[kt][2] = f2bf(fmaxf(d0.z + pv[kt][2], 0.f));
                af[kt][3] = f2bf(fmaxf(d0.w + pv[kt][3], 0.f));
                af[kt][4] = f2bf(fmaxf(d1.x + pv[kt][4], 0.f));
                af[kt][5] = f2bf(fmaxf(d1.y + pv[kt][5], 0.f));
                af[kt][6] = f2bf(fmaxf(d1.z + pv[kt][6], 0.f));
                af[kt][7] = f2bf(fmaxf(d1.w + pv[kt][7], 0.f));
            }
            f32x4 acc[4];
            #pragma unroll
            for (int nt = 0; nt < 4; ++nt)
                acc[nt] = (f32x4){bdr[nt], bdr[nt], bdr[nt], bdr[nt]};
            #pragma unroll
            for (int kt = 0; kt < 4; ++kt)
                #pragma unroll
                for (int nt = 0; nt < 4; ++nt)
                    acc[nt] = __builtin_amdgcn_mfma_f32_16x16x32_bf16(
                        af[kt], bf[kt][nt], acc[nt], 0, 0, 0);

            // h = relu(acc); D-layout: col(kh-part)=q, row(lyi-part)=g*4+reg
            float cp0 = 0.f, cp1 = 0.f, cp2 = 0.f, cp3 = 0.f;
            #pragma unroll
            for (int nt = 0; nt < 4; ++nt) {
                float h0 = fmaxf(acc[nt][0], 0.f);
                float h1 = fmaxf(acc[nt][1], 0.f);
                float h2 = fmaxf(acc[nt][2], 0.f);
                float h3 = fmaxf(acc[nt][3], 0.f);
                hy[nt][0] += h0; hy[nt][1] += h1;
                hy[nt][2] += h2; hy[nt][3] += h3;
                float s = (h0 + h1) + (h2 + h3);
                s += __shfl_xor(s, 16);
                s += __shfl_xor(s, 32);
                if      (nt == 0) cp0 = s;
                else if (nt == 1) cp1 = s;
                else if (nt == 2) cp2 = s;
                else              cp3 = s;
            }
            float cpv = (g == 0) ? cp0 : (g == 1) ? cp1 : (g == 2) ? cp2 : cp3;
            atomicAdd(&un.r.compH[lxi][(g << 4) + q], cpv);
        }
        // flush Hy partials for this lyg (16 rows of protH)
        #pragma unroll
        for (int nt = 0; nt < 4; ++nt)
            #pragma unroll
            for (int r = 0; r < 4; ++r)
                atomicAdd(&un.r.protH[lyg * 16 + (g << 2) + r][nt * 16 + q],
                          hy[nt][r]);
    }
    __syncthreads();

    // ---- block partials -> global (f32 atomics) ----
    for (int u2 = t; u2 < 32 * 64; u2 += 256) {
        int r = u2 >> 6, c = u2 & 63;
        atomicAdd(&Hx[((long)(b * LX_ + lxblk * 32 + r)) * 64 + c], un.r.compH[r][c]);
    }
    for (int u2 = t; u2 < 64 * 64; u2 += 256) {
        int r = u2 >> 6, c = u2 & 63;
        atomicAdd(&Hy[((long)(b * LY_ + lyblk * 64 + r)) * 64 + c], un.r.protH[r][c]);
    }
}

// ---------------- K3: comp/prot = (H * invN) @ W_up + b_up -> gate -> out ------------
__global__ __launch_bounds__(256) void k3_gate(
    const float* __restrict__ H,    // [B*L][64]
    const float* __restrict__ wup,  // [64][128]
    const float* __restrict__ bup,  // [128]
    const float* __restrict__ xin, float* __restrict__ outp,
    int L, float invN)
{
    const int b = blockIdx.y, l0 = blockIdx.x * 32;
    const int t = threadIdx.x;
    __shared__ float Ht[32][68];
    __shared__ float Wt[64][132];
    __shared__ float gg[32][132];
    for (int u = t; u < 32 * 64; u += 256)
        Ht[u >> 6][u & 63] = H[((long)b * L + l0) * 64 + u];
    for (int u = t; u < 64 * 128; u += 256)
        Wt[u >> 7][u & 127] = wup[u];
    __syncthreads();

    const int r = t >> 3, c0 = (t & 7) * 16;
    float acc[16];
    #pragma unroll
    for (int i = 0; i < 16; ++i) acc[i] = 0.f;
    #pragma unroll 4
    for (int k = 0; k < 64; ++k) {
        float hv = Ht[r][k];
        #pragma unroll
        for (int j = 0; j < 4; ++j) {
            float4 wv = *(const float4*)&Wt[k][c0 + 4 * j];
            acc[4 * j + 0] = fmaf(hv, wv.x, acc[4 * j + 0]);
            acc[4 * j + 1] = fmaf(hv, wv.y, acc[4 * j + 1]);
            acc[4 * j + 2] = fmaf(hv, wv.z, acc[4 * j + 2]);
            acc[4 * j + 3] = fmaf(hv, wv.w, acc[4 * j + 3]);
        }
    }
    #pragma unroll
    for (int i = 0; i < 16; ++i) {
        float v = fmaf(acc[i], invN, bup[c0 + i]);
        float sg = 1.f / (1.f + expf(-v));
        gg[r][c0 + i] = sg * tanhf(v);
    }
    __syncthreads();
    for (int u = t; u < 32 * 128; u += 256) {
        int c = u >> 5, li = u & 31;
        long idx = ((long)b * C_ + c) * L + l0 + li;
        outp[idx] = xin[idx] * (0.5f + gg[li][c]);
    }
}

extern "C" void kernel_launch(void* const* d_in, const int* in_sizes, int n_in,
                              void* d_out, int out_size, void* d_ws, size_t ws_size,
                              hipStream_t stream) {
    (void)in_sizes; (void)n_in; (void)out_size; (void)ws_size;
    const float* x     = (const float*)d_in[0];
    const float* y     = (const float*)d_in[1];
    const float* Wdrug = (const float*)d_in[2];
    const float* bdrug = (const float*)d_in[3];
    const float* Wprot = (const float*)d_in[4];
    const float* bprot = (const float*)d_in[5];
    const float* Wdown = (const float*)d_in[6];
    const float* bdown = (const float*)d_in[7];
    const float* Wup   = (const float*)d_in[8];
    const float* bup   = (const float*)d_in[9];
    float* out = (float*)d_out;
    float* ws  = (float*)d_ws;

    float* datt = ws;                   // B*LX*C  = 131072
    float* patt = ws + 131072;          // B*LY*C  = 1048576
    float* Hx   = ws + 1179648;         // B*LX*64 = 65536
    float* Hy   = ws + 1245184;         // B*LY*64 = 524288
    // zero region: Hx+Hy = 589824 floats = 147456 float4 -> 576 blocks

    hipLaunchKernelGGL(k_zero, dim3(576), dim3(256), 0, stream, (float4*)Hx);
    hipLaunchKernelGGL(k1_att, dim3(2304), dim3(128), 0, stream,
                       x, y, Wdrug, bdrug, Wprot, bprot, datt, patt);
    hipLaunchKernelGGL(k2_main, dim3(16, 4, 8), dim3(256), 0, stream,
                       datt, patt, Wdown, bdown, Hx, Hy);
    hipLaunchKernelGGL(k3_gate, dim3(4, 8), dim3(256), 0, stream,
                       Hx, Wup, bup, x, out, LX_, 1.f / 1024.f);
    hipLaunchKernelGGL(k3_gate, dim3(32, 8), dim3(256), 0, stream,
                       Hy, Wup, bup, y, out + (long)B_ * C_ * LX_, LY_, 1.f / 128.f);
}